// Round 1
// baseline (1977.898 us; speedup 1.0000x reference)
//
#include <hip/hip_runtime.h>
#include <stdint.h>

// Problem constants (fixed by reference)
#define VOC 32000
#define HD  768
#define NHD 12
#define DH  64
#define FF  3072
#define NL  6
#define BB  4
#define SS  512

typedef __bf16 bf16;
typedef __attribute__((ext_vector_type(8))) __bf16 bf16x8;
typedef __attribute__((ext_vector_type(4))) float f32x4;

// async global->LDS, 16B per lane. LDS dest must be wave-uniform base; HW adds lane*16.
__device__ __forceinline__ void ld_g2l_16(const bf16* g, bf16* lds_base) {
  __builtin_amdgcn_global_load_lds(
      (const __attribute__((address_space(1))) uint32_t*)g,
      (__attribute__((address_space(3))) uint32_t*)lds_base,
      16, 0, 0);
}

// ---------------------------------------------------------------------------
// Generic bf16 MFMA GEMM: C[M,N] = alpha * A[M,K] @ Bt[N,K]^T (+bias)(+res)(relu)
// BM=128 fixed, BN in {128,64}. 256 threads = 4 waves (2x2), 16x16x32 bf16 MFMA.
// Batched over blockIdx.z with (inner,outer) strides: z = zo*z_inner + zi.
// ---------------------------------------------------------------------------
template<int BN, bool RELU>
__global__ __launch_bounds__(256)
void gemm_kernel(const bf16* __restrict__ A, const bf16* __restrict__ B,
                 int K, int lda, int ldb, int ldc, int z_inner,
                 long long sAi, long long sAo, long long sBi, long long sBo,
                 long long sCi, long long sCo,
                 const float* __restrict__ bias, int sBias,
                 const float* __restrict__ res, float alpha,
                 float* __restrict__ outF, bf16* __restrict__ outB)
{
  constexpr int BM = 128, BK = 32;
  __shared__ bf16 As[BM * BK];
  __shared__ bf16 Bs[BN * BK];

  const int zi = blockIdx.z % z_inner;
  const int zo = blockIdx.z / z_inner;

  const bf16* Ab = A + (long long)zo * sAo + (long long)zi * sAi;
  const bf16* Bb = B + (long long)zo * sBo + (long long)zi * sBi;
  const long long coff = (long long)zo * sCo + (long long)zi * sCi;

  const int m0 = blockIdx.y * BM;
  const int n0 = blockIdx.x * BN;
  const int t = threadIdx.x;
  const int wave = t >> 6;
  const int lane = t & 63;
  const int wm = (wave >> 1) * 64;        // wave row offset in tile
  const int wn = (wave & 1) * (BN / 2);   // wave col offset in tile
  const int lr = lane & 15;               // A-row / B-col / C-col within 16
  const int ko = (lane >> 4) * 8;         // k-octet

  constexpr int NACC = BN / 32;           // 16-col tiles per wave
  f32x4 acc[4][NACC];
  const f32x4 zero4 = {0.f, 0.f, 0.f, 0.f};
#pragma unroll
  for (int i = 0; i < 4; ++i)
#pragma unroll
    for (int j = 0; j < NACC; ++j) acc[i][j] = zero4;

  constexpr int CA = (BM * BK / 8) / 256; // 16B chunks per thread (A)
  constexpr int CB = (BN * BK / 8) / 256; // (B)

  for (int k0 = 0; k0 < K; k0 += BK) {
    __syncthreads();
#pragma unroll
    for (int c = 0; c < CA; ++c) {
      int chunk = c * 256 + t;
      int r = chunk >> 2;
      int kk = (chunk & 3) << 3;
      ld_g2l_16(Ab + (long long)(m0 + r) * lda + (k0 + kk),
                &As[(c * 256 + wave * 64) * 8]);
    }
#pragma unroll
    for (int c = 0; c < CB; ++c) {
      int chunk = c * 256 + t;
      int r = chunk >> 2;
      int kk = (chunk & 3) << 3;
      ld_g2l_16(Bb + (long long)(n0 + r) * ldb + (k0 + kk),
                &Bs[(c * 256 + wave * 64) * 8]);
    }
    __syncthreads();

    bf16x8 af[4];
#pragma unroll
    for (int mi = 0; mi < 4; ++mi)
      af[mi] = *(const bf16x8*)&As[(wm + mi * 16 + lr) * BK + ko];
    bf16x8 bfr[NACC];
#pragma unroll
    for (int ni = 0; ni < NACC; ++ni)
      bfr[ni] = *(const bf16x8*)&Bs[(wn + ni * 16 + lr) * BK + ko];
#pragma unroll
    for (int mi = 0; mi < 4; ++mi)
#pragma unroll
      for (int ni = 0; ni < NACC; ++ni)
        acc[mi][ni] = __builtin_amdgcn_mfma_f32_16x16x32_bf16(
            af[mi], bfr[ni], acc[mi][ni], 0, 0, 0);
  }

  // Epilogue. C/D layout: col = lane&15, row = (lane>>4)*4 + reg  [m89/m91]
  const int r4 = (lane >> 4) * 4;
#pragma unroll
  for (int ni = 0; ni < NACC; ++ni) {
    const int col = n0 + wn + ni * 16 + lr;
    float bv = bias ? bias[(long long)zi * sBias + col] : 0.f;
#pragma unroll
    for (int mi = 0; mi < 4; ++mi) {
#pragma unroll
      for (int r = 0; r < 4; ++r) {
        const int row = m0 + wm + mi * 16 + r4 + r;
        const long long idx = coff + (long long)row * ldc + col;
        float v = acc[mi][ni][r] * alpha + bv;
        if (res) v += res[idx];
        if (RELU) v = fmaxf(v, 0.f);
        if (outF) outF[idx] = v;
        if (outB) outB[idx] = (bf16)v;
      }
    }
  }
}

// ---------------------------------------------------------------------------
// fp32 [K,N] -> bf16 [N,K] transpose-convert (per z matrix)
// ---------------------------------------------------------------------------
__global__ void transpose_cvt(const float* __restrict__ in, bf16* __restrict__ out,
                              int K, int N, long long inZ, long long outZ)
{
  __shared__ float tile[32][33];
  const float* ip = in + (long long)blockIdx.z * inZ;
  bf16* op = out + (long long)blockIdx.z * outZ;
  int n0 = blockIdx.x * 32, k0 = blockIdx.y * 32;
  int tx = threadIdx.x, ty = threadIdx.y;
#pragma unroll
  for (int j = 0; j < 32; j += 8)
    tile[ty + j][tx] = ip[(long long)(k0 + ty + j) * N + n0 + tx];
  __syncthreads();
#pragma unroll
  for (int j = 0; j < 32; j += 8)
    op[(long long)(n0 + ty + j) * K + k0 + tx] = (bf16)tile[tx][ty + j];
}

// bf16 V [B,S,NH*DH] -> Vt [B,NH,DH,S]
__global__ void vtrans(const bf16* __restrict__ v, bf16* __restrict__ vt)
{
  __shared__ bf16 tile[32][33];
  int z = blockIdx.z;                 // b*NH + h
  int b = z / NHD, h = z % NHD;
  int s0 = blockIdx.x * 32, d0 = blockIdx.y * 32;
  int tx = threadIdx.x, ty = threadIdx.y;
  const bf16* ip = v + (long long)b * SS * HD + (long long)h * DH;
#pragma unroll
  for (int j = 0; j < 32; j += 8)
    tile[ty + j][tx] = ip[(long long)(s0 + ty + j) * HD + d0 + tx];
  __syncthreads();
  bf16* op = vt + (long long)z * DH * SS;
#pragma unroll
  for (int j = 0; j < 32; j += 8)
    op[(long long)(d0 + ty + j) * SS + s0 + tx] = tile[tx][ty + j];
}

// pack bq,bk,bv [L,H] -> [L,3,H]
__global__ void pack_bias(const float* __restrict__ bq, const float* __restrict__ bk,
                          const float* __restrict__ bv, float* __restrict__ o)
{
  int i = blockIdx.x * 256 + threadIdx.x;
  if (i >= NL * 3 * HD) return;
  int l = i / (3 * HD);
  int r = i % (3 * HD);
  int sel = r / HD, j = r % HD;
  const float* src = (sel == 0) ? bq : (sel == 1) ? bk : bv;
  o[i] = src[l * HD + j];
}

// x = emb[tok] + pos ; write fp32 + bf16
__global__ void embed_k(const int* __restrict__ tok, const float* __restrict__ emb,
                        const float* __restrict__ pos, float* __restrict__ hf,
                        bf16* __restrict__ hb)
{
  int row = blockIdx.x;               // b*SS + s
  int s = row % SS;
  int tk = tok[row];
  const float* e = emb + (long long)tk * HD;
  const float* p = pos + (long long)s * HD;
#pragma unroll
  for (int j = 0; j < 3; ++j) {
    int c = threadIdx.x + j * 256;
    float v = e[c] + p[c];
    hf[(long long)row * HD + c] = v;
    hb[(long long)row * HD + c] = (bf16)v;
  }
}

// row softmax over S=512 with padding mask; in-place fp32, bf16 copy.
// one wave per row, 4 rows per block
__global__ void softmax_k(float* __restrict__ sc, bf16* __restrict__ pb,
                          const int* __restrict__ tok)
{
  int wave = threadIdx.x >> 6, lane = threadIdx.x & 63;
  int row = blockIdx.x * 4 + wave;    // (b*NH + h)*SS + q
  int b = row / (NHD * SS);
  float* rp = sc + (long long)row * SS;
  const int* tp = tok + b * SS;
  float x[8];
  float mx = -1e30f;
#pragma unroll
  for (int j = 0; j < 8; ++j) {
    int c = lane + j * 64;
    float v = rp[c];
    if (tp[c] == 0) v -= 10000.f;
    x[j] = v;
    mx = fmaxf(mx, v);
  }
#pragma unroll
  for (int off = 1; off < 64; off <<= 1) mx = fmaxf(mx, __shfl_xor(mx, off));
  float sum = 0.f;
#pragma unroll
  for (int j = 0; j < 8; ++j) { x[j] = __expf(x[j] - mx); sum += x[j]; }
#pragma unroll
  for (int off = 1; off < 64; off <<= 1) sum += __shfl_xor(sum, off);
  float inv = 1.f / sum;
#pragma unroll
  for (int j = 0; j < 8; ++j) {
    int c = lane + j * 64;
    float p = x[j] * inv;
    rp[c] = p;
    pb[(long long)row * SS + c] = (bf16)p;
  }
}

// LayerNorm over H=768; writes fp32 dest + bf16 dest
__global__ void ln_k(const float* __restrict__ x, const float* __restrict__ g,
                     const float* __restrict__ be, float* __restrict__ of,
                     bf16* __restrict__ ob)
{
  int row = blockIdx.x;
  const float* xp = x + (long long)row * HD;
  float vals[3];
  float s = 0.f, ss = 0.f;
#pragma unroll
  for (int j = 0; j < 3; ++j) {
    float v = xp[threadIdx.x + j * 256];
    vals[j] = v;
    s += v;
    ss += v * v;
  }
#pragma unroll
  for (int off = 1; off < 64; off <<= 1) {
    s += __shfl_xor(s, off);
    ss += __shfl_xor(ss, off);
  }
  __shared__ float S1[4], S2[4];
  int wave = threadIdx.x >> 6, lane = threadIdx.x & 63;
  if (lane == 0) { S1[wave] = s; S2[wave] = ss; }
  __syncthreads();
  s = S1[0] + S1[1] + S1[2] + S1[3];
  ss = S2[0] + S2[1] + S2[2] + S2[3];
  const float rH = 1.f / (float)HD;
  float mean = s * rH;
  float var = ss * rH - mean * mean;
  float rstd = rsqrtf(var + 1e-12f);
#pragma unroll
  for (int j = 0; j < 3; ++j) {
    int c = threadIdx.x + j * 256;
    float y = (vals[j] - mean) * rstd * g[c] + be[c];
    of[(long long)row * HD + c] = y;
    ob[(long long)row * HD + c] = (bf16)y;
  }
}

// ---------------------------------------------------------------------------
extern "C" void kernel_launch(void* const* d_in, const int* in_sizes, int n_in,
                              void* d_out, int out_size, void* d_ws, size_t ws_size,
                              hipStream_t stream)
{
  (void)in_sizes; (void)n_in; (void)out_size; (void)ws_size;
  const int*   tok = (const int*)  d_in[0];
  const float* emb = (const float*)d_in[1];
  const float* pos = (const float*)d_in[2];
  const float* wq  = (const float*)d_in[3];
  const float* bq  = (const float*)d_in[4];
  const float* wk  = (const float*)d_in[5];
  const float* bk  = (const float*)d_in[6];
  const float* wv  = (const float*)d_in[7];
  const float* bv  = (const float*)d_in[8];
  const float* wo  = (const float*)d_in[9];
  const float* bo  = (const float*)d_in[10];
  const float* g1  = (const float*)d_in[11];
  const float* be1 = (const float*)d_in[12];
  const float* w1  = (const float*)d_in[13];
  const float* b1  = (const float*)d_in[14];
  const float* w2  = (const float*)d_in[15];
  const float* b2  = (const float*)d_in[16];
  const float* g2  = (const float*)d_in[17];
  const float* be2 = (const float*)d_in[18];
  float* out = (float*)d_out;

  // workspace carve-up (~155 MB total)
  char* p = (char*)d_ws;
  auto alloc = [&](size_t bytes) {
    char* r = p;
    p += (bytes + 255) & ~(size_t)255;
    return r;
  };
  const long long HH   = (long long)HD * HD;       // 589824
  const long long WPL  = 4 * HH + 2 * (long long)HD * FF; // 7077888 bf16/layer
  const long long MH   = (long long)BB * SS * HD;  // 1572864
  const long long ATT  = (long long)BB * NHD * SS * SS; // 12582912

  bf16*  WT    = (bf16*) alloc((size_t)(WPL * NL) * 2);
  float* bqkv  = (float*)alloc((size_t)NL * 3 * HD * 4);
  float* hf    = (float*)alloc((size_t)MH * 4);
  float* preln = (float*)alloc((size_t)MH * 4);
  bf16*  hb    = (bf16*) alloc((size_t)MH * 2);
  bf16*  qkvb  = (bf16*) alloc((size_t)3 * MH * 2);
  bf16*  vt    = (bf16*) alloc((size_t)MH * 2);
  bf16*  attnb = (bf16*) alloc((size_t)ATT * 2);
  bf16*  ctxb  = (bf16*) alloc((size_t)MH * 2);
  bf16*  u     = (bf16*) alloc((size_t)BB * SS * FF * 2);

  dim3 tb(32, 8);
  // weights: fp32 [K,N] -> bf16 [N,K] per layer slot
  transpose_cvt<<<dim3(HD/32, HD/32, NL), tb, 0, stream>>>(wq, WT + 0,      HD, HD, HH, WPL);
  transpose_cvt<<<dim3(HD/32, HD/32, NL), tb, 0, stream>>>(wk, WT + HH,     HD, HD, HH, WPL);
  transpose_cvt<<<dim3(HD/32, HD/32, NL), tb, 0, stream>>>(wv, WT + 2*HH,   HD, HD, HH, WPL);
  transpose_cvt<<<dim3(HD/32, HD/32, NL), tb, 0, stream>>>(wo, WT + 3*HH,   HD, HD, HH, WPL);
  transpose_cvt<<<dim3(FF/32, HD/32, NL), tb, 0, stream>>>(w1, WT + 4*HH,   HD, FF, (long long)HD*FF, WPL);
  transpose_cvt<<<dim3(HD/32, FF/32, NL), tb, 0, stream>>>(w2, WT + 4*HH + (long long)HD*FF, FF, HD, (long long)HD*FF, WPL);

  pack_bias<<<dim3((NL * 3 * HD + 255) / 256), 256, 0, stream>>>(bq, bk, bv, bqkv);
  embed_k<<<dim3(BB * SS), 256, 0, stream>>>(tok, emb, pos, hf, hb);

  const long long OUT0 = MH;

  for (int l = 0; l < NL; ++l) {
    const bf16* WQT = WT + (long long)l * WPL;
    const bf16* WKT = WQT + HH;
    const bf16* WVT = WQT + 2 * HH;
    const bf16* WOT = WQT + 3 * HH;
    const bf16* W1T = WQT + 4 * HH;
    const bf16* W2T = WQT + 4 * HH + (long long)HD * FF;
    (void)WKT; (void)WVT;

    // 1. QKV projections (batched z=3 over contiguous Wq/Wk/Wv, bias packed)
    gemm_kernel<128,false><<<dim3(HD/128, (BB*SS)/128, 3), 256, 0, stream>>>(
        hb, WQT, HD, HD, HD, HD, 3,
        0, 0, HH, 0, MH, 0,
        bqkv + (long long)l * 3 * HD, HD, nullptr, 1.f, nullptr, qkvb);

    // 2. V -> Vt [B,NH,DH,S]
    vtrans<<<dim3(SS/32, DH/32, BB*NHD), tb, 0, stream>>>(qkvb + 2 * MH, vt);

    // 3. scores = scale * Q @ K^T   (per b,h), fp32 into d_out attn slice
    gemm_kernel<128,false><<<dim3(SS/128, SS/128, BB*NHD), 256, 0, stream>>>(
        qkvb, qkvb + MH, DH, HD, HD, SS, NHD,
        DH, (long long)SS*HD, DH, (long long)SS*HD,
        (long long)SS*SS, (long long)NHD*SS*SS,
        nullptr, 0, nullptr, 0.125f, out + OUT0 + (long long)l * ATT, nullptr);

    // 4. masked softmax (in-place fp32 + bf16 P)
    softmax_k<<<dim3(BB*NHD*SS/4), 256, 0, stream>>>(
        out + OUT0 + (long long)l * ATT, attnb, tok);

    // 5. ctx = P @ V  -> bf16 [B,S,H]
    gemm_kernel<64,false><<<dim3(DH/64, SS/128, BB*NHD), 256, 0, stream>>>(
        attnb, vt, SS, SS, SS, HD, NHD,
        (long long)SS*SS, (long long)NHD*SS*SS, (long long)DH*SS, (long long)NHD*DH*SS,
        DH, (long long)SS*HD,
        nullptr, 0, nullptr, 1.f, nullptr, ctxb);

    // 6. O-projection + bias + residual(x)
    gemm_kernel<128,false><<<dim3(HD/128, (BB*SS)/128, 1), 256, 0, stream>>>(
        ctxb, WOT, HD, HD, HD, HD, 1,
        0, 0, 0, 0, 0, 0,
        bo + (long long)l * HD, 0, hf, 1.f, preln, nullptr);

    // 7. LN1 -> hf, hb
    ln_k<<<dim3(BB*SS), 256, 0, stream>>>(preln, g1 + (long long)l*HD, be1 + (long long)l*HD, hf, hb);

    // 8. FFN1 + bias + relu -> u (bf16)
    gemm_kernel<128,true><<<dim3(FF/128, (BB*SS)/128, 1), 256, 0, stream>>>(
        hb, W1T, HD, HD, HD, FF, 1,
        0, 0, 0, 0, 0, 0,
        b1 + (long long)l * FF, 0, nullptr, 1.f, nullptr, u);

    // 9. FFN2 + bias + residual(hf)
    gemm_kernel<128,false><<<dim3(HD/128, (BB*SS)/128, 1), 256, 0, stream>>>(
        u, W2T, FF, FF, FF, HD, 1,
        0, 0, 0, 0, 0, 0,
        b2 + (long long)l * HD, 0, hf, 1.f, preln, nullptr);

    // 10. LN2 -> (hf or final out), hb
    ln_k<<<dim3(BB*SS), 256, 0, stream>>>(preln, g2 + (long long)l*HD, be2 + (long long)l*HD,
                                          (l == NL - 1) ? out : hf, hb);
  }
}